// Round 2
// baseline (385.367 us; speedup 1.0000x reference)
//
#include <hip/hip_runtime.h>
#include <stdint.h>

// Problem constants (fixed by reference setup_inputs)
constexpr int N    = 8192;
constexpr int D    = 512;
constexpr int KEXT = 8;
constexpr int NCLS = 1000;
#define TAU_INV 14.285714285714285714f   // 1/0.07

constexpr int BM = 128, BN = 128, BK = 64;
constexpr int NB   = N / BM;             // 64 tile-rows
constexpr int NBLK = NB * (NB + 1) / 2;  // 2080 upper-tri tiles

typedef _Float16 half8 __attribute__((ext_vector_type(8)));
typedef _Float16 half4 __attribute__((ext_vector_type(4)));
typedef float    f32x4 __attribute__((ext_vector_type(4)));

typedef __attribute__((address_space(1))) void gvoid;
typedef __attribute__((address_space(3))) void lvoid;

// ---------------- small prep kernels ----------------

__global__ void zero_k(float* pos, float* neg) {
    int i = blockIdx.x * blockDim.x + threadIdx.x;
    if (i < N) { pos[i] = 0.f; neg[i] = 0.f; }
}

// single-block LDS histogram: counts + inverse counts in one launch
__global__ void hist_k(const int* __restrict__ y, int* __restrict__ counts,
                       float* __restrict__ invc) {
    __shared__ int h[NCLS];
    int tid = threadIdx.x;                 // 1024 threads
    for (int i = tid; i < NCLS; i += 1024) h[i] = 0;
    __syncthreads();
    for (int i = tid; i < N; i += 1024) atomicAdd(&h[y[i]], 1);
    __syncthreads();
    for (int i = tid; i < NCLS; i += 1024) {
        int c = h[i];
        counts[i] = c;
        invc[i]   = 1.0f / (float)c;       // classes with count 0 never indexed
    }
}

// f32 -> f16 convert of q (N*D elems), vectorized x4
__global__ void cvt_k(const float* __restrict__ q, _Float16* __restrict__ qh) {
    int i = blockIdx.x * blockDim.x + threadIdx.x;   // over N*D/4
    float4 v = reinterpret_cast<const float4*>(q)[i];
    half4 o;
    o.x = (_Float16)v.x; o.y = (_Float16)v.y; o.z = (_Float16)v.z; o.w = (_Float16)v.w;
    reinterpret_cast<half4*>(qh)[i] = o;
}

// ---------------- fused symmetric GEMM (q @ q^T) + contrastive epilogue ----
// Upper-triangular tiles only. 128x128 tile, BK=64, 4 waves in 2x2, each wave
// 64x64 via 4x4 grid of 16x16x32 f16 MFMAs, 2 K-substeps per LDS tile.
// LDS layout XOR-swizzled at 16B granularity: granule g of row R stored at
// g ^ (R&7)  ->  conflict-free ds_read_b128 fragment loads, and the swizzle is
// applied on the per-lane GLOBAL source address so the wave-uniform-base DMA
// (global_load_lds) constraint holds and coalescing is unchanged.
__global__ __launch_bounds__(256) void gemm_k(
        const _Float16* __restrict__ qh,
        const int* __restrict__ y,
        const float* __restrict__ invc,
        float* __restrict__ pos_sum,
        float* __restrict__ neg_sum) {
    __shared__ _Float16 As[BM * BK];     // 16 KB, row stride 128 B (8 granules)
    __shared__ _Float16 Bs[BN * BK];     // 16 KB
    __shared__ int   yis[BM];
    __shared__ int   yjs[BN];
    __shared__ float icsA[BM];
    __shared__ float icsB[BN];

    const int tid  = threadIdx.x;
    const int wave = tid >> 6;
    const int lane = tid & 63;
    const int quad = lane >> 4;
    const int l15  = lane & 15;

    // ---- decode upper-triangular tile index ----
    const int t = blockIdx.x;
    int bi = (int)(((float)(2 * NB + 1) -
                    sqrtf((float)((2 * NB + 1) * (2 * NB + 1)) - 8.0f * (float)t)) * 0.5f);
    if (bi < 0) bi = 0;
    if (bi > NB - 1) bi = NB - 1;
    // tri_start(b) = b*NB - b*(b-1)/2
    while ((bi + 1) * NB - ((bi + 1) * bi >> 1) <= t) ++bi;
    while (bi * NB - (bi * (bi - 1) >> 1) > t) --bi;
    const int bj = bi + (t - (bi * NB - (bi * (bi - 1) >> 1)));
    const int ibase = bi * BM, jbase = bj * BN;

    if (tid < BM) {
        int yi = y[ibase + tid];
        int yj = y[jbase + tid];
        yis[tid] = yi;  icsA[tid] = invc[yi];
        yjs[tid] = yj;  icsB[tid] = invc[yj];
    }

    // wave position within the 128x128 tile (2x2 waves of 64x64)
    const int wr = (wave >> 1) * 64;
    const int wc = (wave & 1) * 64;

    f32x4 acc[4][4];
#pragma unroll
    for (int a = 0; a < 4; a++)
#pragma unroll
        for (int b = 0; b < 4; b++) acc[a][b] = (f32x4)0.0f;

    // staging: wave w stages rows [w*32, w*32+32) of A and B as 4 chunks of
    // 8 rows (1 KB each). lane -> (row rr = lane>>3, LDS granule lane&7);
    // swizzle: fetch global granule (lane&7) ^ (rr&7).
    const int rr = lane >> 3;                        // 0..7 row within chunk
    const int gg = ((lane & 7) ^ (rr & 7)) * 8;      // halves offset in row
    const _Float16* gA = qh + (size_t)(ibase + wave * 32 + rr) * D + gg;
    const _Float16* gB = qh + (size_t)(jbase + wave * 32 + rr) * D + gg;
    char* ldsA = (char*)As + wave * 4096;            // wave's 32-row region
    char* ldsB = (char*)Bs + wave * 4096;

    for (int k0 = 0; k0 < D; k0 += BK) {
        __syncthreads();   // prior iter's ds_reads done before overwrite
#pragma unroll
        for (int c = 0; c < 4; c++) {
            __builtin_amdgcn_global_load_lds((gvoid*)(gA + (size_t)c * 8 * D + k0),
                                             (lvoid*)(ldsA + c * 1024), 16, 0, 0);
            __builtin_amdgcn_global_load_lds((gvoid*)(gB + (size_t)c * 8 * D + k0),
                                             (lvoid*)(ldsB + c * 1024), 16, 0, 0);
        }
        __syncthreads();   // implicit s_waitcnt vmcnt(0) drains the LDS-DMA

#pragma unroll
        for (int ks = 0; ks < 2; ks++) {
            half8 af[4], bfr[4];
#pragma unroll
            for (int mi = 0; mi < 4; mi++) {
                int row = wr + mi * 16 + l15;
                int g   = ((ks * 4 + quad) ^ (l15 & 7)) * 16;
                af[mi] = *reinterpret_cast<const half8*>((const char*)As + row * 128 + g);
            }
#pragma unroll
            for (int mj = 0; mj < 4; mj++) {
                int row = wc + mj * 16 + l15;
                int g   = ((ks * 4 + quad) ^ (l15 & 7)) * 16;
                bfr[mj] = *reinterpret_cast<const half8*>((const char*)Bs + row * 128 + g);
            }
#pragma unroll
            for (int mi = 0; mi < 4; mi++)
#pragma unroll
                for (int mj = 0; mj < 4; mj++)
                    acc[mi][mj] = __builtin_amdgcn_mfma_f32_16x16x32_f16(af[mi], bfr[mj], acc[mi][mj], 0, 0, 0);
        }
    }

    // ---- epilogue: masked exp + row/col reductions ----
    int   yjv[4];
    float icj[4];
#pragma unroll
    for (int mj = 0; mj < 4; mj++) {
        int jl = wc + mj * 16 + l15;
        yjv[mj] = yjs[jl];
        icj[mj] = icsB[jl];
    }

    if (bi == bj) {
        // diagonal tile: both orders of each pair are in-tile; row-side only
#pragma unroll
        for (int mi = 0; mi < 4; mi++) {
#pragma unroll
            for (int r = 0; r < 4; r++) {
                const int il   = wr + mi * 16 + quad * 4 + r;   // C/D: row = quad*4+reg
                const int irow = ibase + il;
                const int yi   = yis[il];
                float posp = 0.f, negp = 0.f;
#pragma unroll
                for (int mj = 0; mj < 4; mj++) {
                    const int jcol = jbase + wc + mj * 16 + l15; // C/D: col = lane&15
                    float a    = acc[mi][mj][r];
                    float e    = __expf(a * TAU_INV);
                    bool  nz   = (a != 0.0f);                    // faithful masked_fill(x==0,-inf)
                    bool  same = (yi == yjv[mj]);
                    posp += (same && (irow != jcol) && nz) ? e : 0.0f;
                    negp += (!same && nz) ? e * icj[mj] : 0.0f;
                }
#pragma unroll
                for (int off = 1; off < 16; off <<= 1) {
                    posp += __shfl_xor(posp, off);
                    negp += __shfl_xor(negp, off);
                }
                if (l15 == 0) {
                    atomicAdd(&pos_sum[irow], posp);
                    atomicAdd(&neg_sum[irow], negp);
                }
            }
        }
    } else {
        // off-diagonal tile: each element (i,j) serves both (i,j) and (j,i)
        float cp[4] = {0.f, 0.f, 0.f, 0.f};
        float cn[4] = {0.f, 0.f, 0.f, 0.f};
#pragma unroll
        for (int mi = 0; mi < 4; mi++) {
#pragma unroll
            for (int r = 0; r < 4; r++) {
                const int il   = wr + mi * 16 + quad * 4 + r;
                const int irow = ibase + il;
                const int yi   = yis[il];
                const float ici = icsA[il];
                float posp = 0.f, negp = 0.f;
#pragma unroll
                for (int mj = 0; mj < 4; mj++) {
                    float a    = acc[mi][mj][r];
                    float e    = __expf(a * TAU_INV);
                    bool  nz   = (a != 0.0f);
                    bool  same = (yi == yjv[mj]);
                    float pe   = (same && nz) ? e : 0.0f;        // i != j guaranteed (bi<bj)
                    posp   += pe;
                    cp[mj] += pe;
                    negp   += (!same && nz) ? e * icj[mj] : 0.0f;
                    cn[mj] += (!same && nz) ? e * ici : 0.0f;
                }
#pragma unroll
                for (int off = 1; off < 16; off <<= 1) {
                    posp += __shfl_xor(posp, off);
                    negp += __shfl_xor(negp, off);
                }
                if (l15 == 0) {
                    atomicAdd(&pos_sum[irow], posp);
                    atomicAdd(&neg_sum[irow], negp);
                }
            }
        }
        // column-side: reduce across the 4 quads (rows), lanes quad==0 commit
#pragma unroll
        for (int mj = 0; mj < 4; mj++) {
            float a = cp[mj], b = cn[mj];
            a += __shfl_xor(a, 16); a += __shfl_xor(a, 32);
            b += __shfl_xor(b, 16); b += __shfl_xor(b, 32);
            if (quad == 0) {
                const int jcol = jbase + wc + mj * 16 + l15;
                atomicAdd(&pos_sum[jcol], a);
                atomicAdd(&neg_sum[jcol], b);
            }
        }
    }
}

// ---------------- per-row finalize: k_sims (fp32) + log ratio ----------------
__global__ void finalize_k(const float* __restrict__ q, const float* __restrict__ kmat,
                           const int* __restrict__ y, const int* __restrict__ counts,
                           const float* __restrict__ pos_sum, const float* __restrict__ neg_sum,
                           float* __restrict__ loss) {
    const int wave = threadIdx.x >> 6, lane = threadIdx.x & 63;
    const int i = blockIdx.x * 4 + wave;

    float qv[8];
#pragma unroll
    for (int t = 0; t < 8; t++) qv[t] = q[(size_t)i * D + t * 64 + lane];

    float esum = 0.f;
    for (int kk = 0; kk < KEXT; kk++) {
        const float* kr = kmat + ((size_t)i * KEXT + kk) * D;
        float p = 0.f;
#pragma unroll
        for (int t = 0; t < 8; t++) p = fmaf(qv[t], kr[t * 64 + lane], p);
#pragma unroll
        for (int off = 1; off < 64; off <<= 1) p += __shfl_xor(p, off);
        esum += __expf(p * TAU_INV);
    }
    if (lane == 0) {
        float num = logf(esum + pos_sum[i]);
        float den = logf(neg_sum[i]);
        float cnt = (float)(counts[y[i]] - 1 + KEXT);  // same_class_counts, label-only
        loss[i] = -(num - den) / cnt;
    }
}

__global__ void reduce_k(const float* __restrict__ loss, float* __restrict__ out) {
    __shared__ float part[16];
    int tid = threadIdx.x;   // 1024 threads
    float s = 0.f;
    for (int i = tid; i < N; i += 1024) s += loss[i];
#pragma unroll
    for (int off = 1; off < 64; off <<= 1) s += __shfl_xor(s, off);
    if ((tid & 63) == 0) part[tid >> 6] = s;
    __syncthreads();
    if (tid < 16) {
        float v = part[tid];
#pragma unroll
        for (int off = 1; off < 16; off <<= 1) v += __shfl_xor(v, off);
        if (tid == 0) out[0] = v / (float)N;
    }
}

// ---------------- launch ----------------
extern "C" void kernel_launch(void* const* d_in, const int* in_sizes, int n_in,
                              void* d_out, int out_size, void* d_ws, size_t ws_size,
                              hipStream_t stream) {
    const float* q    = (const float*)d_in[0];
    const float* kmat = (const float*)d_in[1];
    const int*   y    = (const int*)d_in[2];
    float* out = (float*)d_out;

    char* ws = (char*)d_ws;
    _Float16* qh   = (_Float16*)ws;                 // 8 MB: N*D f16
    int*   counts  = (int*)  (ws + 8388608);        // 1000 ints
    float* invc    = (float*)(ws + 8392704);        // 1000 floats
    float* pos     = (float*)(ws + 8396800);        // N floats
    float* neg     = (float*)(ws + 8429568);        // N floats
    float* loss    = (float*)(ws + 8462336);        // N floats

    zero_k    <<<32, 256, 0, stream>>>(pos, neg);
    hist_k    <<<1, 1024, 0, stream>>>(y, counts, invc);
    cvt_k     <<<(N * D / 4) / 256, 256, 0, stream>>>(q, qh);
    gemm_k    <<<NBLK, 256, 0, stream>>>(qh, y, invc, pos, neg);
    finalize_k<<<N / 4, 256, 0, stream>>>(q, kmat, y, counts, pos, neg, loss);
    reduce_k  <<<1, 1024, 0, stream>>>(loss, out);
}